// Round 3
// baseline (1882.194 us; speedup 1.0000x reference)
//
#include <hip/hip_runtime.h>

// EIRNN: B=256,T=512,I=128,H=512,O=64; alpha=0.2, softplus beta=8, thresh=20.
// R3: tag-in-data exchange. h element stored as u32 {tag=t+1 | f16(h)} with
// relaxed agent-scope (sc1) dword stores -- single-copy atomic, so consumer
// gather loads ARE the readiness poll (retry u64s whose tags != t). Removes
// R2's flag store, flag poll, and producer s_waitcnt(0) drain (~3 coherence
// round-trips/step). Single barrier/step (hg+xsh double-buffered); readout
// atomics drain inside next gather's waits. Self-shard h goes via LDS.
// ABA-safe: lock-step prevents slot reuse before all consumers advance;
// 16-bit tag is exact for t<=512. ws re-poison 0xAAAA != any tag.

#define BB 256
#define TT 512
#define II 128
#define HH 512
#define OO 64
#define RG 16   // batch rows per row-group
#define JC 64   // h-columns per shard block
#define NG 16   // row-groups
#define NC 8    // shard blocks per group
#define HGP (HH + 8)
#define XP  (II + 8)

typedef _Float16 f16;
typedef f16 f16x8 __attribute__((ext_vector_type(8)));
typedef float f32x4 __attribute__((ext_vector_type(4)));

__global__ __launch_bounds__(256, 1)
void eirnn_persist(const float* __restrict__ x,
                   const float* __restrict__ Wxh,
                   const float* __restrict__ Whh,
                   const float* __restrict__ bh,
                   const float* __restrict__ Wout,
                   const float* __restrict__ bout,
                   float* __restrict__ yout,
                   unsigned int* __restrict__ hbuf)  // [2][BB][HH] u32 (1 MB)
{
    const int tid  = threadIdx.x;
    const int bid  = blockIdx.x;
    const int wave = tid >> 6;
    const int lane = tid & 63;
    const int quad = lane >> 4;
    const int l16  = lane & 15;
    const int r    = bid >> 3;        // row-group
    const int c    = bid & 7;         // shard
    const int rowbase = r * RG;
    const int jbase   = c * JC;
    const int myrow   = wave * 16 + l16;

    __shared__ __align__(16) f16 hg[2][RG][HGP];   // double-buffered gathered h
    __shared__ __align__(16) f16 xsh[2][RG][XP];   // double-buffered x_t

    // ---- one-time: weight shards -> constant register B-fragments ----
    // B-frag: lane holds BT[n=lane&15][k=quad*8+j], j=0..7 (verified R1/R2)
    f16x8 bf[16];   // W_hh shard, K=512
    f16x8 xbf[4];   // W_xh shard, K=128
    f16x8 bfo[2];   // W_out K-slice [c*64, c*64+64)
    {
        const float* wp = Whh + (size_t)(jbase + myrow) * HH + quad * 8;
        #pragma unroll
        for (int ks = 0; ks < 16; ++ks) {
            float4 u = *(const float4*)(wp + ks * 32);
            float4 v = *(const float4*)(wp + ks * 32 + 4);
            f16x8 tv;
            tv[0]=(f16)u.x; tv[1]=(f16)u.y; tv[2]=(f16)u.z; tv[3]=(f16)u.w;
            tv[4]=(f16)v.x; tv[5]=(f16)v.y; tv[6]=(f16)v.z; tv[7]=(f16)v.w;
            bf[ks] = tv;
        }
        const float* wq = Wxh + (size_t)(jbase + myrow) * II + quad * 8;
        #pragma unroll
        for (int ks = 0; ks < 4; ++ks) {
            float4 u = *(const float4*)(wq + ks * 32);
            float4 v = *(const float4*)(wq + ks * 32 + 4);
            f16x8 tv;
            tv[0]=(f16)u.x; tv[1]=(f16)u.y; tv[2]=(f16)u.z; tv[3]=(f16)u.w;
            tv[4]=(f16)v.x; tv[5]=(f16)v.y; tv[6]=(f16)v.z; tv[7]=(f16)v.w;
            xbf[ks] = tv;
        }
        const float* wo = Wout + (size_t)myrow * HH + c * 64 + quad * 8;
        #pragma unroll
        for (int ks = 0; ks < 2; ++ks) {
            float4 u = *(const float4*)(wo + ks * 32);
            float4 v = *(const float4*)(wo + ks * 32 + 4);
            f16x8 tv;
            tv[0]=(f16)u.x; tv[1]=(f16)u.y; tv[2]=(f16)u.z; tv[3]=(f16)u.w;
            tv[4]=(f16)v.x; tv[5]=(f16)v.y; tv[6]=(f16)v.z; tv[7]=(f16)v.w;
            bfo[ks] = tv;
        }
    }
    const float biash = bh[jbase + myrow];
    const float biaso = (c == 0) ? bout[myrow] : 0.0f;

    // zero hg[0] (t=0 uses h_0=0); hg[1] fully covered by gather+self-write
    for (int p = tid; p < RG * HGP / 2; p += 256)
        ((unsigned int*)hg[0])[p] = 0u;

    // fp32 integrator state: lane owns h[m=quad*4+reg][jbase+myrow]
    float hreg[4] = {0.f, 0.f, 0.f, 0.f};

    // gather geometry: thread owns cols {2*tid, 2*tid+1} of ALL 16 rows
    // (one u64 per row). Own-shard cols short-circuit via LDS self-write.
    const bool own = ((tid >> 5) == c);

    // x prefetch for t=0
    float4 xpf0, xpf1;
    {
        int p0 = tid, p1 = tid + 256;
        xpf0 = ((const float4*)(x + ((size_t)(rowbase + (p0 >> 5)) * TT + 0) * II))[p0 & 31];
        xpf1 = ((const float4*)(x + ((size_t)(rowbase + (p1 >> 5)) * TT + 0) * II))[p1 & 31];
    }

    for (int t = 0; t <= TT; ++t) {
        const int p = t & 1;

        // ---- stage x_t, then issue x_{t+1} prefetch ----
        if (t < TT) {
            int p0 = tid, p1 = tid + 256;
            f16* d0 = &xsh[p][p0 >> 5][(p0 & 31) * 4];
            d0[0]=(f16)xpf0.x; d0[1]=(f16)xpf0.y; d0[2]=(f16)xpf0.z; d0[3]=(f16)xpf0.w;
            f16* d1 = &xsh[p][p1 >> 5][(p1 & 31) * 4];
            d1[0]=(f16)xpf1.x; d1[1]=(f16)xpf1.y; d1[2]=(f16)xpf1.z; d1[3]=(f16)xpf1.w;
            if (t + 1 < TT) {
                xpf0 = ((const float4*)(x + ((size_t)(rowbase + (p0 >> 5)) * TT + (t + 1)) * II))[p0 & 31];
                xpf1 = ((const float4*)(x + ((size_t)(rowbase + (p1 >> 5)) * TT + (t + 1)) * II))[p1 & 31];
            }
        }

        // ---- tagged gather of h(t): loads ARE the poll; retry stale u64s ----
        if (t >= 1 && !own) {
            const unsigned tg = (unsigned)t;
            const unsigned long long* src = (const unsigned long long*)hbuf
                + (size_t)p * (BB * HH / 2) + (size_t)rowbase * (HH / 2) + tid;
            unsigned long long v[16];
            #pragma unroll
            for (int k = 0; k < 16; ++k)
                v[k] = __hip_atomic_load(src + (size_t)k * (HH / 2),
                                         __ATOMIC_RELAXED, __HIP_MEMORY_SCOPE_AGENT);
            unsigned pend = 0xffffu;
            while (pend) {
                unsigned np = 0;
                #pragma unroll
                for (int k = 0; k < 16; ++k) {
                    if (pend & (1u << k)) {
                        unsigned lo = (unsigned)v[k];
                        unsigned hi = (unsigned)(v[k] >> 32);
                        if (((lo >> 16) == tg) & ((hi >> 16) == tg)) {
                            // pack two f16 payloads -> one b32 LDS write
                            *(unsigned int*)&hg[p][k][2 * tid] = (lo & 0xffffu) | (hi << 16);
                        } else {
                            np |= (1u << k);
                        }
                    }
                }
                pend = np;
                if (np) {
                    #pragma unroll
                    for (int k = 0; k < 16; ++k)
                        if (np & (1u << k))
                            v[k] = __hip_atomic_load(src + (size_t)k * (HH / 2),
                                                     __ATOMIC_RELAXED, __HIP_MEMORY_SCOPE_AGENT);
                }
            }
        }
        __syncthreads();   // single barrier per step

        if (t < TT) {
            // pre = h_t.W_hh^T + x_t.W_xh^T + b_h
            f32x4 acc0 = {0.f,0.f,0.f,0.f}, acc1 = {0.f,0.f,0.f,0.f};
            #pragma unroll
            for (int ks = 0; ks < 16; ks += 2) {
                f16x8 a0 = *(const f16x8*)&hg[p][l16][ks * 32 + quad * 8];
                f16x8 a1 = *(const f16x8*)&hg[p][l16][(ks + 1) * 32 + quad * 8];
                acc0 = __builtin_amdgcn_mfma_f32_16x16x32_f16(a0, bf[ks], acc0, 0, 0, 0);
                acc1 = __builtin_amdgcn_mfma_f32_16x16x32_f16(a1, bf[ks + 1], acc1, 0, 0, 0);
            }
            #pragma unroll
            for (int ks = 0; ks < 4; ks += 2) {
                f16x8 a0 = *(const f16x8*)&xsh[p][l16][ks * 32 + quad * 8];
                f16x8 a1 = *(const f16x8*)&xsh[p][l16][(ks + 1) * 32 + quad * 8];
                acc0 = __builtin_amdgcn_mfma_f32_16x16x32_f16(a0, xbf[ks], acc0, 0, 0, 0);
                acc1 = __builtin_amdgcn_mfma_f32_16x16x32_f16(a1, xbf[ks + 1], acc1, 0, 0, 0);
            }
            // phi + leaky update; fire-and-forget tagged u32 stores (no drain!)
            unsigned int* dst = hbuf + (size_t)((t + 1) & 1) * (BB * HH);
            const unsigned tg1 = (unsigned)(t + 1) << 16;
            #pragma unroll
            for (int reg = 0; reg < 4; ++reg) {
                float pre = acc0[reg] + acc1[reg] + biash;
                float z = 8.f * pre;
                float ph = (z > 20.f) ? pre : (__logf(1.f + __expf(z)) * 0.125f);
                float hn = 0.8f * hreg[reg] + 0.2f * ph;
                hreg[reg] = hn;
                f16 h16 = (f16)hn;
                // self-shard short-circuit into next hg buffer (post-barrier: safe)
                hg[1 - p][quad * 4 + reg][jbase + myrow] = h16;
                unsigned hb = (unsigned)__builtin_bit_cast(unsigned short, h16);
                __hip_atomic_store(dst + (size_t)(rowbase + quad * 4 + reg) * HH + jbase + myrow,
                                   tg1 | hb, __ATOMIC_RELAXED, __HIP_MEMORY_SCOPE_AGENT);
            }
        }

        // ---- readout partial: y_{t-1} += h_t[:, c*64:+64].W_out^T ----
        // issued AFTER h stores; atomics drain inside next gather's waits
        if (t >= 1) {
            f32x4 ya = {0.f,0.f,0.f,0.f};
            f16x8 a0 = *(const f16x8*)&hg[p][l16][c * 64 + quad * 8];
            f16x8 a1 = *(const f16x8*)&hg[p][l16][c * 64 + 32 + quad * 8];
            ya = __builtin_amdgcn_mfma_f32_16x16x32_f16(a0, bfo[0], ya, 0, 0, 0);
            ya = __builtin_amdgcn_mfma_f32_16x16x32_f16(a1, bfo[1], ya, 0, 0, 0);
            #pragma unroll
            for (int reg = 0; reg < 4; ++reg)
                atomicAdd(yout + ((size_t)(rowbase + quad * 4 + reg) * TT + (t - 1)) * OO + myrow,
                          ya[reg] + biaso);
        }
    }
}

extern "C" void kernel_launch(void* const* d_in, const int* in_sizes, int n_in,
                              void* d_out, int out_size, void* d_ws, size_t ws_size,
                              hipStream_t stream)
{
    const float* x    = (const float*)d_in[0];
    const float* Wxh  = (const float*)d_in[1];
    const float* Whh  = (const float*)d_in[2];
    const float* bh   = (const float*)d_in[3];
    const float* Wout = (const float*)d_in[4];
    const float* bout = (const float*)d_in[5];
    float* yout = (float*)d_out;

    unsigned int* hbuf = (unsigned int*)d_ws;           // [2][BB][HH] u32 = 1 MB
    const size_t hbuf_bytes = (size_t)2 * BB * HH * sizeof(unsigned int);
    if (ws_size < hbuf_bytes) return;

    // d_out zeroed for K-split atomic readout (ws/out re-poisoned each launch;
    // poison tag 0xAAAA matches no t in [1,512], so hbuf needs no init)
    hipMemsetAsync(yout, 0, (size_t)out_size * sizeof(float), stream);

    // 128 blocks, 256 threads, ~42 KB LDS, 1 block/CU co-resident
    eirnn_persist<<<dim3(NG * NC), dim3(256), 0, stream>>>(
        x, Wxh, Whh, bh, Wout, bout, yout, hbuf);
}